// Round 1
// baseline (535.131 us; speedup 1.0000x reference)
//
#include <hip/hip_runtime.h>
#include <cmath>

#define DW 300
#define HH 128
#define G3 384
#define GN 768
#define SS 256
#define BBATCH 128
#define NC 10
#define DC 16
#define NCDC 160
#define CAP_EPS 1e-7f

__device__ __forceinline__ float sigmoidf_(float x) {
  return 1.0f / (1.0f + __expf(-x));
}
__device__ __forceinline__ float tanhf_(float x) {
  float e = __expf(2.0f * x);
  return 1.0f - 2.0f / (e + 1.0f);
}

#define FMA16()                                                                \
  acc[0][0] += a.x * bv.x; acc[0][1] += a.x * bv.y;                            \
  acc[0][2] += a.x * bv.z; acc[0][3] += a.x * bv.w;                            \
  acc[1][0] += a.y * bv.x; acc[1][1] += a.y * bv.y;                            \
  acc[1][2] += a.y * bv.z; acc[1][3] += a.y * bv.w;                            \
  acc[2][0] += a.z * bv.x; acc[2][1] += a.z * bv.y;                            \
  acc[2][2] += a.z * bv.z; acc[2][3] += a.z * bv.w;                            \
  acc[3][0] += a.w * bv.x; acc[3][1] += a.w * bv.y;                            \
  acc[3][2] += a.w * bv.z; acc[3][3] += a.w * bv.w;

// K1: xp[m][n] = sum_k emb[x(m)][k] * w(n)[k] + bias(n)
// m = s*128 + b; n < 384 -> forward weights, else backward.
__global__ __launch_bounds__(256) void k1_xproj(
    const int* __restrict__ x, const float* __restrict__ emb,
    const float* __restrict__ wf, const float* __restrict__ wb,
    const float* __restrict__ bf, const float* __restrict__ bb,
    float* __restrict__ xp)
{
  __shared__ __align__(16) float As[60][64];
  __shared__ __align__(16) float Bs[60][64];
  __shared__ int rows[64];
  const int tid = threadIdx.x;
  const int m0 = blockIdx.x * 64;
  const int n0 = blockIdx.y * 64;

  if (tid < 64) {
    const int m = m0 + tid;
    const int b = m & 127;
    const int s = m >> 7;
    rows[tid] = x[b * SS + s];
  }
  __syncthreads();

  const int tx = tid & 15;      // col group (4 cols)
  const int ty = tid >> 4;      // row group (4 rows)
  const int lr = tid >> 2;      // load row/col 0..63
  const int lq = tid & 3;       // quarter of 60 k's (15 each)

  const int arow = rows[lr];
  const int nA = n0 + lr;
  const float* __restrict__ wrow =
      (nA < G3) ? (wf + (size_t)nA * DW) : (wb + (size_t)(nA - G3) * DW);
  const float* __restrict__ arowp = emb + (size_t)arow * DW;

  float acc[4][4] = {{0.f, 0.f, 0.f, 0.f}, {0.f, 0.f, 0.f, 0.f},
                     {0.f, 0.f, 0.f, 0.f}, {0.f, 0.f, 0.f, 0.f}};

  for (int k0 = 0; k0 < DW; k0 += 60) {
    const float* asrc = arowp + k0 + lq * 15;
    const float* bsrc = wrow + k0 + lq * 15;
#pragma unroll
    for (int i = 0; i < 15; ++i) As[lq * 15 + i][lr] = asrc[i];
#pragma unroll
    for (int i = 0; i < 15; ++i) Bs[lq * 15 + i][lr] = bsrc[i];
    __syncthreads();
#pragma unroll
    for (int k = 0; k < 60; ++k) {
      const float4 a  = *(const float4*)&As[k][ty * 4];
      const float4 bv = *(const float4*)&Bs[k][tx * 4];
      FMA16();
    }
    __syncthreads();
  }

  const int nn = n0 + tx * 4;
  const float* bvp = (n0 < G3) ? (bf + nn) : (bb + (nn - G3));
  const float4 bias = *(const float4*)bvp;
#pragma unroll
  for (int i = 0; i < 4; ++i) {
    float4 v = make_float4(acc[i][0] + bias.x, acc[i][1] + bias.y,
                           acc[i][2] + bias.z, acc[i][3] + bias.w);
    *(float4*)&xp[(size_t)(m0 + ty * 4 + i) * GN + nn] = v;
  }
}

// K2: GRU recurrence. One block per (dir, batch element): 256 blocks x 384 thr.
// Thread g holds w_hh row g in registers; h broadcast via LDS.
__global__ __launch_bounds__(384) void k2_gru(
    const float* __restrict__ xp,
    const float* __restrict__ whf, const float* __restrict__ whb,
    const float* __restrict__ bhf, const float* __restrict__ bhb,
    float* __restrict__ hcat)
{
  const int bid = blockIdx.x;
  const int dir = bid >> 7;
  const int b   = bid & 127;
  const int g   = threadIdx.x;   // 0..383
  const int grp = g >> 7;        // 0:r 1:z 2:n
  const int j   = g & 127;

  const float* __restrict__ wh = dir ? whb : whf;
  const float* __restrict__ bh = dir ? bhb : bhf;

  float w[128];
  {
    const float* src = wh + (size_t)g * HH;
#pragma unroll
    for (int v = 0; v < 32; ++v) {
      const float4 d = *(const float4*)(src + 4 * v);
      w[4 * v + 0] = d.x; w[4 * v + 1] = d.y;
      w[4 * v + 2] = d.z; w[4 * v + 3] = d.w;
    }
  }
  const float bias = bh[g];

  __shared__ __align__(16) float hbuf[HH];
  __shared__ float rbuf[HH];
  __shared__ float zbuf[HH];
  if (g < HH) hbuf[g] = 0.f;
  __syncthreads();

  const float* __restrict__ xpd = xp + dir * G3;
  const int step = dir ? -1 : 1;
  int s = dir ? (SS - 1) : 0;
  float xg = xpd[((size_t)s * BBATCH + b) * GN + g];

  for (int it = 0; it < SS; ++it) {
    const int s_cur = s;
    const float xcur = xg;
    if (it < SS - 1) {
      s += step;
      xg = xpd[((size_t)s * BBATCH + b) * GN + g];   // prefetch next step
    }
    float d0 = 0.f, d1 = 0.f, d2 = 0.f, d3 = 0.f;
#pragma unroll
    for (int v = 0; v < 32; ++v) {
      const float4 h4 = *(const float4*)&hbuf[4 * v];
      d0 += w[4 * v + 0] * h4.x;
      d1 += w[4 * v + 1] * h4.y;
      d2 += w[4 * v + 2] * h4.z;
      d3 += w[4 * v + 3] * h4.w;
    }
    const float hp = (d0 + d1) + (d2 + d3) + bias;
    if (grp == 0) {
      rbuf[j] = sigmoidf_(xcur + hp);
    } else if (grp == 1) {
      zbuf[j] = sigmoidf_(xcur + hp);
    }
    __syncthreads();
    if (grp == 2) {
      const float r = rbuf[j];
      const float n = tanhf_(xcur + r * hp);
      const float z = zbuf[j];
      const float hnew = (1.f - z) * n + z * hbuf[j];
      hbuf[j] = hnew;
      hcat[((size_t)b * SS + s_cur) * 256 + dir * HH + j] = hnew;
    }
    __syncthreads();
  }
}

// K3: uh[m][n] = sum_k hcat[m][k] * Wc[k][n]; m = b*256+s.
__global__ __launch_bounds__(256) void k3_uhat(
    const float* __restrict__ hcat, const float* __restrict__ Wc,
    float* __restrict__ uh)
{
  __shared__ __align__(16) float As[64][128];
  __shared__ __align__(16) float Bs[64][32];
  const int tid = threadIdx.x;
  const int m0 = blockIdx.x * 128;
  const int n0 = blockIdx.y * 32;
  const int tx = tid & 7;     // col group
  const int ty = tid >> 3;    // row group 0..31
  const int lr  = tid >> 1;   // A load row 0..127
  const int lh  = tid & 1;    // k half
  const int bkr = tid >> 2;   // B load k row 0..63
  const int bq  = tid & 3;    // B 8-col chunk

  float acc[4][4] = {{0.f, 0.f, 0.f, 0.f}, {0.f, 0.f, 0.f, 0.f},
                     {0.f, 0.f, 0.f, 0.f}, {0.f, 0.f, 0.f, 0.f}};

  for (int k0 = 0; k0 < 256; k0 += 64) {
    const float* asrc = hcat + (size_t)(m0 + lr) * 256 + k0 + lh * 32;
#pragma unroll
    for (int v = 0; v < 8; ++v) {
      const float4 d = *(const float4*)(asrc + 4 * v);
      const int kk = lh * 32 + 4 * v;
      As[kk + 0][lr] = d.x; As[kk + 1][lr] = d.y;
      As[kk + 2][lr] = d.z; As[kk + 3][lr] = d.w;
    }
    const float* bsrc = Wc + (size_t)(k0 + bkr) * NCDC + n0 + bq * 8;
    *(float4*)&Bs[bkr][bq * 8]     = *(const float4*)bsrc;
    *(float4*)&Bs[bkr][bq * 8 + 4] = *(const float4*)(bsrc + 4);
    __syncthreads();
#pragma unroll
    for (int k = 0; k < 64; ++k) {
      const float4 a  = *(const float4*)&As[k][ty * 4];
      const float4 bv = *(const float4*)&Bs[k][tx * 4];
      FMA16();
    }
    __syncthreads();
  }
#pragma unroll
  for (int i = 0; i < 4; ++i) {
    float4 v = make_float4(acc[i][0], acc[i][1], acc[i][2], acc[i][3]);
    *(float4*)&uh[(size_t)(m0 + ty * 4 + i) * NCDC + n0 + tx * 4] = v;
  }
}

// K4: dynamic routing + final linear. One block per batch element.
__global__ __launch_bounds__(256) void k4_route(
    const float* __restrict__ uhat, const float* __restrict__ Wl,
    const float* __restrict__ bl, float* __restrict__ outp)
{
  const int b = blockIdx.x;
  const int t = threadIdx.x;
  __shared__ float blog[NC][SS + 1];
  __shared__ float cbuf[NC][SS + 1];
  __shared__ float vout[NC][DC];
  __shared__ float red0[256], red1[256];

  const float* __restrict__ u = uhat + (size_t)b * SS * NCDC;

#pragma unroll
  for (int i = 0; i < NC; ++i) blog[i][t] = 0.f;
  __syncthreads();

  const int ci = t >> 4, ck = t & 15;
  float myval = 0.f;

  for (int it = 0; it < 5; ++it) {
    // softmax over capsules, column j = t
    float m = blog[0][t];
#pragma unroll
    for (int i = 1; i < NC; ++i) m = fmaxf(m, blog[i][t]);
    float e[NC];
    float sum = 0.f;
#pragma unroll
    for (int i = 0; i < NC; ++i) { e[i] = __expf(blog[i][t] - m); sum += e[i]; }
    const float inv = 1.0f / sum;
#pragma unroll
    for (int i = 0; i < NC; ++i) cbuf[i][t] = e[i] * inv;
    __syncthreads();

    if (t < NCDC) {
      float acc = 0.f;
#pragma unroll 4
      for (int jj = 0; jj < SS; ++jj)
        acc += cbuf[ci][jj] * u[(size_t)jj * NCDC + t];
      float ss = acc * acc;
      ss += __shfl_xor(ss, 1);
      ss += __shfl_xor(ss, 2);
      ss += __shfl_xor(ss, 4);
      ss += __shfl_xor(ss, 8);
      myval = acc / sqrtf(ss + CAP_EPS);
      vout[ci][ck] = myval;
    }
    __syncthreads();

    if (it < 4) {
      const float* ur = u + (size_t)t * NCDC;
#pragma unroll
      for (int i = 0; i < NC; ++i) {
        float dot = 0.f;
#pragma unroll
        for (int k = 0; k < DC; ++k) dot += ur[i * DC + k] * vout[i][k];
        blog[i][t] += dot;
      }
      __syncthreads();
    }
  }

  float p0 = 0.f, p1 = 0.f;
  if (t < NCDC) { p0 = myval * Wl[2 * t]; p1 = myval * Wl[2 * t + 1]; }
  red0[t] = p0; red1[t] = p1;
  __syncthreads();
  for (int off = 128; off >= 1; off >>= 1) {
    if (t < off) { red0[t] += red0[t + off]; red1[t] += red1[t + off]; }
    __syncthreads();
  }
  if (t == 0) {
    outp[2 * b + 0] = red0[0] + bl[0];
    outp[2 * b + 1] = red1[0] + bl[1];
  }
}

extern "C" void kernel_launch(void* const* d_in, const int* in_sizes, int n_in,
                              void* d_out, int out_size, void* d_ws, size_t ws_size,
                              hipStream_t stream) {
  (void)in_sizes; (void)n_in; (void)out_size; (void)ws_size;
  const int*   x    = (const int*)  d_in[0];
  const float* emb  = (const float*)d_in[1];
  const float* wif  = (const float*)d_in[2];
  const float* whf  = (const float*)d_in[3];
  const float* bif  = (const float*)d_in[4];
  const float* bhf  = (const float*)d_in[5];
  const float* wib  = (const float*)d_in[6];
  const float* whb  = (const float*)d_in[7];
  const float* bib  = (const float*)d_in[8];
  const float* bhb  = (const float*)d_in[9];
  const float* Wc   = (const float*)d_in[10];
  const float* Wl   = (const float*)d_in[11];
  const float* bl   = (const float*)d_in[12];
  float* out = (float*)d_out;

  float* xp   = (float*)d_ws;                          // [32768][768]  100.7 MB
  float* hcat = xp + (size_t)32768 * GN;               // [32768][256]   33.6 MB
  float* uh   = hcat + (size_t)32768 * 256;            // [32768][160]   21.0 MB

  dim3 g1(512, 12);
  hipLaunchKernelGGL(k1_xproj, g1, dim3(256), 0, stream, x, emb, wif, wib, bif, bib, xp);
  hipLaunchKernelGGL(k2_gru, dim3(256), dim3(384), 0, stream, xp, whf, whb, bhf, bhb, hcat);
  dim3 g3(256, 5);
  hipLaunchKernelGGL(k3_uhat, g3, dim3(256), 0, stream, hcat, Wc, uh);
  hipLaunchKernelGGL(k4_route, dim3(128), dim3(256), 0, stream, uh, Wl, bl, out);
}